// Round 1
// baseline (172.061 us; speedup 1.0000x reference)
//
#include <hip/hip_runtime.h>
#include <math.h>

typedef _Float16 f16_t;
typedef __attribute__((ext_vector_type(8))) _Float16 f16x8;
typedef __attribute__((ext_vector_type(4))) float f32x4;

#define NTOK 131072
#define MT   128      // tokens per block
#define TPB  256      // 4 waves; each wave owns 32 tokens; ZERO barriers
#define RP16 72       // relay pitch (f16)
#define OP32 68       // out-stage pitch (f32)
#define SLABB 4608    // per-wave slab: relay 32*72*2=4608 B; d3 stages 16 rows (4352 B) at a time

// ws layout (f16 elems)
#define OFF_KEY 0
#define OFF_VAL 4096
#define OFF_T   8192
#define OFF_D1  40960
#define OFF_D2  45056
#define OFF_D3  47104
#define WTOT    49152

__device__ __forceinline__ f32x4 mfma1(f16x8 a, f16x8 b, f32x4 c) {
    return __builtin_amdgcn_mfma_f32_16x16x32_f16(a, b, c, 0, 0, 0);
}

struct B2 { f16x8 b0, b1; };
__device__ __forceinline__ B2 loadB(const f16_t* __restrict__ bw, int c, int l15, int quad) {
    const f16_t* p = bw + (16 * c + l15) * 64 + quad * 8;
    B2 r; r.b0 = *(const f16x8*)p; r.b1 = *(const f16x8*)(p + 32); return r;
}

// one column-tile GEMM step on NAMED vars (no arrays anywhere)
#define GEMMC(bw, c, a00, a01, a10, a11, acc0, acc1) do {        \
    B2 Bf = loadB((bw), (c), l15, quad);                          \
    acc0 = mfma1(a01, Bf.b1, mfma1(a00, Bf.b0, acc0));            \
    acc1 = mfma1(a11, Bf.b1, mfma1(a10, Bf.b0, acc1));            \
} while (0)

// ---------------- prep: transpose all weights into ws as fp16 --------------
__global__ __launch_bounds__(256)
void prep_w(const float* __restrict__ keyW, const float* __restrict__ valW,
            const float* __restrict__ TW,   const float* __restrict__ TB,
            const float* __restrict__ d1W,  const float* __restrict__ d2W,
            const float* __restrict__ d3W,  f16_t* __restrict__ wsf)
{
    int idx = blockIdx.x * 256 + threadIdx.x;
    if (idx >= WTOT) return;
    float src;
    if (idx < OFF_VAL) {
        int r = idx - OFF_KEY, n = r >> 6, j = r & 63;
        src = keyW[j * 64 + n];
    } else if (idx < OFF_T) {
        int r = idx - OFF_VAL, n = r >> 6, j = r & 63;
        src = valW[j * 64 + n];
    } else if (idx < OFF_D1) {
        int r = idx - OFF_T, p = r >> 12, q = r & 4095;
        src = (p < 7) ? TW[p * 4096 + q] : TB[q];
    } else if (idx < OFF_D2) {
        int r = idx - OFF_D1, n = r >> 6, j = r & 63;
        src = d1W[j * 64 + n];
    } else if (idx < OFF_D3) {
        int r = idx - OFF_D2, n = r >> 6, j = r & 63;
        src = d2W[j * 32 + n];
    } else {
        int r = idx - OFF_D3, n = r >> 5, j = r & 31;
        src = d3W[j * 64 + n];
    }
    wsf[idx] = (f16_t)src;
}

// per-row-tile front: combined k|v GEMM + softmax + att + normalize + relay.
// All value parameters, all named locals — nothing can lower to scratch.
__device__ __forceinline__ void front_rt(
    f16_t* __restrict__ Rf, const f16_t* __restrict__ wsf,
    int l15, int quad, int rtb,
    f16x8 a0, f16x8 a1,
    f32x4 q0, f32x4 q1, f32x4 q2, f32x4 q3,
    f32x4 kbv, f32x4 vbv, float sc)
{
    const f16_t* wkv = wsf + OFF_KEY;
    f32x4 k0 = {}, k1 = {}, k2 = {}, k3 = {}, v0 = {}, v1 = {}, v2 = {}, v3 = {};
    { B2 B = loadB(wkv, 0, l15, quad); k0 = mfma1(a1, B.b1, mfma1(a0, B.b0, k0)); }
    { B2 B = loadB(wkv, 1, l15, quad); k1 = mfma1(a1, B.b1, mfma1(a0, B.b0, k1)); }
    { B2 B = loadB(wkv, 2, l15, quad); k2 = mfma1(a1, B.b1, mfma1(a0, B.b0, k2)); }
    { B2 B = loadB(wkv, 3, l15, quad); k3 = mfma1(a1, B.b1, mfma1(a0, B.b0, k3)); }
    { B2 B = loadB(wkv, 4, l15, quad); v0 = mfma1(a1, B.b1, mfma1(a0, B.b0, v0)); }
    { B2 B = loadB(wkv, 5, l15, quad); v1 = mfma1(a1, B.b1, mfma1(a0, B.b0, v1)); }
    { B2 B = loadB(wkv, 6, l15, quad); v2 = mfma1(a1, B.b1, mfma1(a0, B.b0, v2)); }
    { B2 B = loadB(wkv, 7, l15, quad); v3 = mfma1(a1, B.b1, mfma1(a0, B.b0, v3)); }

    f32x4 sv0 = (v0 + vbv[0]) * sc;
    f32x4 sv1 = (v1 + vbv[1]) * sc;
    f32x4 sv2 = (v2 + vbv[2]) * sc;
    f32x4 sv3 = (v3 + vbv[3]) * sc;

    f32x4 mx;
#pragma unroll
    for (int e = 0; e < 4; ++e)
        mx[e] = fmaxf(fmaxf(sv0[e], sv1[e]), fmaxf(sv2[e], sv3[e]));
#pragma unroll
    for (int m = 1; m < 16; m <<= 1)
#pragma unroll
        for (int e = 0; e < 4; ++e) mx[e] = fmaxf(mx[e], __shfl_xor(mx[e], m, 64));
#pragma unroll
    for (int e = 0; e < 4; ++e) {
        sv0[e] = __expf(sv0[e] - mx[e]);
        sv1[e] = __expf(sv1[e] - mx[e]);
        sv2[e] = __expf(sv2[e] - mx[e]);
        sv3[e] = __expf(sv3[e] - mx[e]);
    }
    f32x4 se = sv0 + sv1 + sv2 + sv3;
#pragma unroll
    for (int m = 1; m < 16; m <<= 1)
#pragma unroll
        for (int e = 0; e < 4; ++e) se[e] += __shfl_xor(se[e], m, 64);

    f32x4 at0 = q0 * (k0 + kbv[0]);
    f32x4 at1 = q1 * (k1 + kbv[1]);
    f32x4 at2 = q2 * (k2 + kbv[2]);
    f32x4 at3 = q3 * (k3 + kbv[3]);
    f32x4 nr = at0 * at0 + at1 * at1 + at2 * at2 + at3 * at3;
#pragma unroll
    for (int m = 1; m < 16; m <<= 1)
#pragma unroll
        for (int e = 0; e < 4; ++e) nr[e] += __shfl_xor(nr[e], m, 64);

    f32x4 fac;
#pragma unroll
    for (int e = 0; e < 4; ++e)
        fac[e] = 1.0f / (fmaxf(sqrtf(nr[e]), 1e-8f) * se[e]);

#pragma unroll
    for (int e = 0; e < 4; ++e) {
        f16_t* rr = Rf + (rtb + quad * 4 + e) * RP16 + l15;
        rr[0]  = (f16_t)(at0[e] * sv0[e] * fac[e]);
        rr[16] = (f16_t)(at1[e] * sv1[e] * fac[e]);
        rr[32] = (f16_t)(at2[e] * sv2[e] * fac[e]);
        rr[48] = (f16_t)(at3[e] * sv3[e] * fac[e]);
    }
}

// ------- main: shrunken slab (4608B/wave) -> 4 blocks/CU resident ----------
__global__ __launch_bounds__(TPB, 4)
void fused_mfma(const float* __restrict__ kv_in, const float* __restrict__ q_in,
                const float* __restrict__ keyB,  const float* __restrict__ valB,
                const float* __restrict__ d1B,   const float* __restrict__ d2B,
                const float* __restrict__ d3B,   const float* __restrict__ scale_p,
                const f16_t* __restrict__ wsf,   float* __restrict__ out)
{
    __shared__ __align__(16) unsigned char Slab[4][SLABB];   // 18432 B
    __shared__ __align__(16) float Qs[8][MT];                // 4096 B -> 22528 total

    const int tid  = threadIdx.x;
    const int wv   = tid >> 6, lane = tid & 63;
    const int quad = lane >> 4, l15 = lane & 15;
    const int RB   = wv * 32;
    const long t0  = (long)blockIdx.x * MT;

    f16_t* __restrict__ Rf = (f16_t*)Slab[wv];
    float* __restrict__ Of = (float*)Slab[wv];

    // ---- coalesced kv staging -> fp16 relay (wave-private) ----
    {
        const int r = lane >> 1, half = lane & 1;
        const float4* p4 = (const float4*)(kv_in + (t0 + RB + r) * 64 + half * 32);
        f16_t* dst = Rf + r * RP16 + half * 32;
#pragma unroll
        for (int b = 0; b < 4; ++b) {
            float4 f0 = p4[2 * b], f1 = p4[2 * b + 1];
            f16x8 h;
            h[0] = (f16_t)f0.x; h[1] = (f16_t)f0.y; h[2] = (f16_t)f0.z; h[3] = (f16_t)f0.w;
            h[4] = (f16_t)f1.x; h[5] = (f16_t)f1.y; h[6] = (f16_t)f1.z; h[7] = (f16_t)f1.w;
            *(f16x8*)(dst + 8 * b) = h;
        }
    }
    // ---- q' -> Qs (wave-private cols) ----
    if (lane < 32) {
        const float* qp = q_in + (t0 + RB + lane) * 7;
#pragma unroll
        for (int p = 0; p < 7; ++p) Qs[p][RB + lane] = qp[p];
        Qs[7][RB + lane] = 1.0f;
    }

    f32x4 kbv, vbv;
#pragma unroll
    for (int c = 0; c < 4; ++c) { kbv[c] = keyB[16 * c + l15]; vbv[c] = valB[16 * c + l15]; }
    const float sc = scale_p[0];

    // ---- A-fragments (named) ----
    f16x8 ah00 = *(const f16x8*)(Rf + l15 * RP16 + quad * 8);
    f16x8 ah01 = *(const f16x8*)(Rf + l15 * RP16 + 32 + quad * 8);
    f16x8 ah10 = *(const f16x8*)(Rf + (16 + l15) * RP16 + quad * 8);
    f16x8 ah11 = *(const f16x8*)(Rf + (16 + l15) * RP16 + 32 + quad * 8);

    // ---- T stage: q = sum_p q'_p * (KV @ T_p^T), named accumulators ----
    f32x4 q00 = {}, q01 = {}, q02 = {}, q03 = {};
    f32x4 q10 = {}, q11 = {}, q12 = {}, q13 = {};
#pragma unroll 1
    for (int p = 0; p < 8; ++p) {
        const f16_t* bt = wsf + OFF_T + p * 4096;
        f32x4 t00 = {}, t01 = {}, t02 = {}, t03 = {};
        f32x4 t10 = {}, t11 = {}, t12 = {}, t13 = {};
        GEMMC(bt, 0, ah00, ah01, ah10, ah11, t00, t10);
        GEMMC(bt, 1, ah00, ah01, ah10, ah11, t01, t11);
        GEMMC(bt, 2, ah00, ah01, ah10, ah11, t02, t12);
        GEMMC(bt, 3, ah00, ah01, ah10, ah11, t03, t13);
        f32x4 qp0 = *(const f32x4*)&Qs[p][RB + quad * 4];
        f32x4 qp1 = *(const f32x4*)&Qs[p][RB + 16 + quad * 4];
        q00 += qp0 * t00; q01 += qp0 * t01; q02 += qp0 * t02; q03 += qp0 * t03;
        q10 += qp1 * t10; q11 += qp1 * t11; q12 += qp1 * t12; q13 += qp1 * t13;
    }

    // ---- per row-tile front (k|v + elementwise + relay) ----
    front_rt(Rf, wsf, l15, quad, 0,  ah00, ah01, q00, q01, q02, q03, kbv, vbv, sc);
    front_rt(Rf, wsf, l15, quad, 16, ah10, ah11, q10, q11, q12, q13, kbv, vbv, sc);

    // ---- d1: h1 = relu(x @ d1 + b1) ----
    f16x8 xh00 = *(const f16x8*)(Rf + l15 * RP16 + quad * 8);
    f16x8 xh01 = *(const f16x8*)(Rf + l15 * RP16 + 32 + quad * 8);
    f16x8 xh10 = *(const f16x8*)(Rf + (16 + l15) * RP16 + quad * 8);
    f16x8 xh11 = *(const f16x8*)(Rf + (16 + l15) * RP16 + 32 + quad * 8);
    {
        const f16_t* wd1 = wsf + OFF_D1;
        f32x4 h00 = {}, h01 = {}, h02 = {}, h03 = {};
        f32x4 h10 = {}, h11 = {}, h12 = {}, h13 = {};
        GEMMC(wd1, 0, xh00, xh01, xh10, xh11, h00, h10);
        GEMMC(wd1, 1, xh00, xh01, xh10, xh11, h01, h11);
        GEMMC(wd1, 2, xh00, xh01, xh10, xh11, h02, h12);
        GEMMC(wd1, 3, xh00, xh01, xh10, xh11, h03, h13);
        f32x4 b1v;
#pragma unroll
        for (int c = 0; c < 4; ++c) b1v[c] = d1B[16 * c + l15];
#pragma unroll
        for (int e = 0; e < 4; ++e) {
            f16_t* r0 = Rf + (quad * 4 + e) * RP16 + l15;
            r0[0]  = (f16_t)fmaxf(h00[e] + b1v[0], 0.f);
            r0[16] = (f16_t)fmaxf(h01[e] + b1v[1], 0.f);
            r0[32] = (f16_t)fmaxf(h02[e] + b1v[2], 0.f);
            r0[48] = (f16_t)fmaxf(h03[e] + b1v[3], 0.f);
            f16_t* r1 = Rf + (16 + quad * 4 + e) * RP16 + l15;
            r1[0]  = (f16_t)fmaxf(h10[e] + b1v[0], 0.f);
            r1[16] = (f16_t)fmaxf(h11[e] + b1v[1], 0.f);
            r1[32] = (f16_t)fmaxf(h12[e] + b1v[2], 0.f);
            r1[48] = (f16_t)fmaxf(h13[e] + b1v[3], 0.f);
        }
    }

    // ---- d2: h2 = relu(h1 @ d2 + b2), 32 cols ----
    xh00 = *(const f16x8*)(Rf + l15 * RP16 + quad * 8);
    xh01 = *(const f16x8*)(Rf + l15 * RP16 + 32 + quad * 8);
    xh10 = *(const f16x8*)(Rf + (16 + l15) * RP16 + quad * 8);
    xh11 = *(const f16x8*)(Rf + (16 + l15) * RP16 + 32 + quad * 8);
    {
        const f16_t* wd2 = wsf + OFF_D2;
        f32x4 g00 = {}, g01 = {}, g10 = {}, g11 = {};
        GEMMC(wd2, 0, xh00, xh01, xh10, xh11, g00, g10);
        GEMMC(wd2, 1, xh00, xh01, xh10, xh11, g01, g11);
        float b20 = d2B[l15], b21 = d2B[16 + l15];
#pragma unroll
        for (int e = 0; e < 4; ++e) {
            f16_t* r0 = Rf + (quad * 4 + e) * RP16 + l15;
            r0[0]  = (f16_t)fmaxf(g00[e] + b20, 0.f);
            r0[16] = (f16_t)fmaxf(g01[e] + b21, 0.f);
            f16_t* r1 = Rf + (16 + quad * 4 + e) * RP16 + l15;
            r1[0]  = (f16_t)fmaxf(g10[e] + b20, 0.f);
            r1[16] = (f16_t)fmaxf(g11[e] + b21, 0.f);
        }
    }

    // ---- d3: out = h2 @ d3 + b3 (K=32) -> two 16-row halves via slab ----
    // A-frags loaded into regs BEFORE the slab is reused as f32 out-stage.
    f16x8 a30 = *(const f16x8*)(Rf + l15 * RP16 + quad * 8);
    f16x8 a31 = *(const f16x8*)(Rf + (16 + l15) * RP16 + quad * 8);
    f32x4 b3v;
#pragma unroll
    for (int c = 0; c < 4; ++c) b3v[c] = d3B[16 * c + l15];
    float* __restrict__ obase = out + (t0 + RB) * 64;

#pragma unroll
    for (int h = 0; h < 2; ++h) {
        const f16x8 a3 = h ? a31 : a30;
#pragma unroll
        for (int c = 0; c < 4; ++c) {
            f16x8 bw = *(const f16x8*)(wsf + OFF_D3 + (16 * c + l15) * 32 + quad * 8);
            f32x4 z = {};
            f32x4 o = mfma1(a3, bw, z);
#pragma unroll
            for (int e = 0; e < 4; ++e)
                Of[(quad * 4 + e) * OP32 + 16 * c + l15] = o[e] + b3v[c];
        }
        // 16-row half: 4 x 1KB contiguous wave-stores (wave-private, no barrier)
#pragma unroll
        for (int i = 0; i < 4; ++i) {
            const int r4 = i * 4 + quad;
            f32x4 v = *(const f32x4*)(Of + r4 * OP32 + l15 * 4);
            *(f32x4*)(obase + h * 1024 + i * 256 + lane * 4) = v;
        }
    }
}

extern "C" void kernel_launch(void* const* d_in, const int* in_sizes, int n_in,
                              void* d_out, int out_size, void* d_ws, size_t ws_size,
                              hipStream_t stream) {
    (void)in_sizes; (void)n_in; (void)out_size; (void)ws_size;
    const float* kv_in = (const float*)d_in[0];
    const float* q_in  = (const float*)d_in[1];
    const float* keyW  = (const float*)d_in[2];
    const float* keyB  = (const float*)d_in[3];
    const float* valW  = (const float*)d_in[4];
    const float* valB  = (const float*)d_in[5];
    const float* TW    = (const float*)d_in[6];
    const float* TB    = (const float*)d_in[7];
    const float* d1W   = (const float*)d_in[8];
    const float* d1B   = (const float*)d_in[9];
    const float* d2W   = (const float*)d_in[10];
    const float* d2B   = (const float*)d_in[11];
    const float* d3W   = (const float*)d_in[12];
    const float* d3B   = (const float*)d_in[13];
    const float* scale = (const float*)d_in[14];
    f16_t* wsf = (f16_t*)d_ws;
    float* outp = (float*)d_out;

    prep_w<<<(WTOT + 255) / 256, 256, 0, stream>>>(keyW, valW, TW, TB, d1W, d2W, d3W, wsf);
    fused_mfma<<<NTOK / MT, TPB, 0, stream>>>(kv_in, q_in, keyB, valB,
                                              d1B, d2B, d3B, scale, wsf, outp);
}

// Round 2
// 158.999 us; speedup vs baseline: 1.0822x; 1.0822x over previous
//
#include <hip/hip_runtime.h>
#include <math.h>

typedef _Float16 f16_t;
typedef __attribute__((ext_vector_type(8))) _Float16 f16x8;
typedef __attribute__((ext_vector_type(4))) float f32x4;

#define NTOK 131072
#define MT   128      // tokens per block
#define TPB  256      // 4 waves; each wave owns 32 tokens; ZERO barriers
#define RP16 72       // relay pitch (f16)
#define OP32 68       // out-stage pitch (f32)
#define SLABB 4608    // per-wave slab: relay 32*72*2=4608 B; d3 stages 16 rows at a time

// ws layout (f16 elems)
#define OFF_KEY 0
#define OFF_VAL 4096
#define OFF_T   8192
#define OFF_D1  40960
#define OFF_D2  45056
#define OFF_D3  47104
#define WTOT    49152

__device__ __forceinline__ f32x4 mfma1(f16x8 a, f16x8 b, f32x4 c) {
    return __builtin_amdgcn_mfma_f32_16x16x32_f16(a, b, c, 0, 0, 0);
}

struct B2 { f16x8 b0, b1; };
__device__ __forceinline__ B2 loadB(const f16_t* __restrict__ bw, int c, int l15, int quad) {
    const f16_t* p = bw + (16 * c + l15) * 64 + quad * 8;
    B2 r; r.b0 = *(const f16x8*)p; r.b1 = *(const f16x8*)(p + 32); return r;
}

// one column-tile GEMM step on NAMED vars (no arrays anywhere)
#define GEMMC(bw, c, a00, a01, a10, a11, acc0, acc1) do {        \
    B2 Bf = loadB((bw), (c), l15, quad);                          \
    acc0 = mfma1(a01, Bf.b1, mfma1(a00, Bf.b0, acc0));            \
    acc1 = mfma1(a11, Bf.b1, mfma1(a10, Bf.b0, acc1));            \
} while (0)

// ---------------- prep: transpose all weights into ws as fp16 --------------
__global__ __launch_bounds__(256)
void prep_w(const float* __restrict__ keyW, const float* __restrict__ valW,
            const float* __restrict__ TW,   const float* __restrict__ TB,
            const float* __restrict__ d1W,  const float* __restrict__ d2W,
            const float* __restrict__ d3W,  f16_t* __restrict__ wsf)
{
    int idx = blockIdx.x * 256 + threadIdx.x;
    if (idx >= WTOT) return;
    float src;
    if (idx < OFF_VAL) {
        int r = idx - OFF_KEY, n = r >> 6, j = r & 63;
        src = keyW[j * 64 + n];
    } else if (idx < OFF_T) {
        int r = idx - OFF_VAL, n = r >> 6, j = r & 63;
        src = valW[j * 64 + n];
    } else if (idx < OFF_D1) {
        int r = idx - OFF_T, p = r >> 12, q = r & 4095;
        src = (p < 7) ? TW[p * 4096 + q] : TB[q];
    } else if (idx < OFF_D2) {
        int r = idx - OFF_D1, n = r >> 6, j = r & 63;
        src = d1W[j * 64 + n];
    } else if (idx < OFF_D3) {
        int r = idx - OFF_D2, n = r >> 6, j = r & 63;
        src = d2W[j * 32 + n];
    } else {
        int r = idx - OFF_D3, n = r >> 5, j = r & 31;
        src = d3W[j * 64 + n];
    }
    wsf[idx] = (f16_t)src;
}

// per-row-tile front: combined k|v GEMM + softmax + att + normalize + relay.
__device__ __forceinline__ void front_rt(
    f16_t* __restrict__ Rf, const f16_t* __restrict__ wsf,
    int l15, int quad, int rtb,
    f16x8 a0, f16x8 a1,
    f32x4 q0, f32x4 q1, f32x4 q2, f32x4 q3,
    f32x4 kbv, f32x4 vbv, float sc)
{
    const f16_t* wkv = wsf + OFF_KEY;
    f32x4 k0 = {}, k1 = {}, k2 = {}, k3 = {}, v0 = {}, v1 = {}, v2 = {}, v3 = {};
    { B2 B = loadB(wkv, 0, l15, quad); k0 = mfma1(a1, B.b1, mfma1(a0, B.b0, k0)); }
    { B2 B = loadB(wkv, 1, l15, quad); k1 = mfma1(a1, B.b1, mfma1(a0, B.b0, k1)); }
    { B2 B = loadB(wkv, 2, l15, quad); k2 = mfma1(a1, B.b1, mfma1(a0, B.b0, k2)); }
    { B2 B = loadB(wkv, 3, l15, quad); k3 = mfma1(a1, B.b1, mfma1(a0, B.b0, k3)); }
    { B2 B = loadB(wkv, 4, l15, quad); v0 = mfma1(a1, B.b1, mfma1(a0, B.b0, v0)); }
    { B2 B = loadB(wkv, 5, l15, quad); v1 = mfma1(a1, B.b1, mfma1(a0, B.b0, v1)); }
    { B2 B = loadB(wkv, 6, l15, quad); v2 = mfma1(a1, B.b1, mfma1(a0, B.b0, v2)); }
    { B2 B = loadB(wkv, 7, l15, quad); v3 = mfma1(a1, B.b1, mfma1(a0, B.b0, v3)); }

    f32x4 sv0 = (v0 + vbv[0]) * sc;
    f32x4 sv1 = (v1 + vbv[1]) * sc;
    f32x4 sv2 = (v2 + vbv[2]) * sc;
    f32x4 sv3 = (v3 + vbv[3]) * sc;

    f32x4 mx;
#pragma unroll
    for (int e = 0; e < 4; ++e)
        mx[e] = fmaxf(fmaxf(sv0[e], sv1[e]), fmaxf(sv2[e], sv3[e]));
#pragma unroll
    for (int m = 1; m < 16; m <<= 1)
#pragma unroll
        for (int e = 0; e < 4; ++e) mx[e] = fmaxf(mx[e], __shfl_xor(mx[e], m, 64));
#pragma unroll
    for (int e = 0; e < 4; ++e) {
        sv0[e] = __expf(sv0[e] - mx[e]);
        sv1[e] = __expf(sv1[e] - mx[e]);
        sv2[e] = __expf(sv2[e] - mx[e]);
        sv3[e] = __expf(sv3[e] - mx[e]);
    }
    f32x4 se = sv0 + sv1 + sv2 + sv3;
#pragma unroll
    for (int m = 1; m < 16; m <<= 1)
#pragma unroll
        for (int e = 0; e < 4; ++e) se[e] += __shfl_xor(se[e], m, 64);

    f32x4 at0 = q0 * (k0 + kbv[0]);
    f32x4 at1 = q1 * (k1 + kbv[1]);
    f32x4 at2 = q2 * (k2 + kbv[2]);
    f32x4 at3 = q3 * (k3 + kbv[3]);
    f32x4 nr = at0 * at0 + at1 * at1 + at2 * at2 + at3 * at3;
#pragma unroll
    for (int m = 1; m < 16; m <<= 1)
#pragma unroll
        for (int e = 0; e < 4; ++e) nr[e] += __shfl_xor(nr[e], m, 64);

    f32x4 fac;
#pragma unroll
    for (int e = 0; e < 4; ++e)
        fac[e] = 1.0f / (fmaxf(sqrtf(nr[e]), 1e-8f) * se[e]);

#pragma unroll
    for (int e = 0; e < 4; ++e) {
        f16_t* rr = Rf + (rtb + quad * 4 + e) * RP16 + l15;
        rr[0]  = (f16_t)(at0[e] * sv0[e] * fac[e]);
        rr[16] = (f16_t)(at1[e] * sv1[e] * fac[e]);
        rr[32] = (f16_t)(at2[e] * sv2[e] * fac[e]);
        rr[48] = (f16_t)(at3[e] * sv3[e] * fac[e]);
    }
}

// ------- main: small slab (4608B/wave, 22528B total) + no-spill codegen ----
// launch_bounds(256,2): VGPR budget 256 -> compiler's natural 88-reg alloc,
// ZERO scratch. (256,4) forced a 64-VGPR squeeze: +75MB spill traffic (R1).
// Runtime packing is resource-driven: min(LDS 7, VGPR 5, grid 4) = 4 blk/CU.
__global__ __launch_bounds__(TPB, 2)
void fused_mfma(const float* __restrict__ kv_in, const float* __restrict__ q_in,
                const float* __restrict__ keyB,  const float* __restrict__ valB,
                const float* __restrict__ d1B,   const float* __restrict__ d2B,
                const float* __restrict__ d3B,   const float* __restrict__ scale_p,
                const f16_t* __restrict__ wsf,   float* __restrict__ out)
{
    __shared__ __align__(16) unsigned char Slab[4][SLABB];   // 18432 B
    __shared__ __align__(16) float Qs[8][MT];                // 4096 B -> 22528 total

    const int tid  = threadIdx.x;
    const int wv   = tid >> 6, lane = tid & 63;
    const int quad = lane >> 4, l15 = lane & 15;
    const int RB   = wv * 32;
    const long t0  = (long)blockIdx.x * MT;

    f16_t* __restrict__ Rf = (f16_t*)Slab[wv];
    float* __restrict__ Of = (float*)Slab[wv];

    // ---- coalesced kv staging -> fp16 relay (wave-private) ----
    {
        const int r = lane >> 1, half = lane & 1;
        const float4* p4 = (const float4*)(kv_in + (t0 + RB + r) * 64 + half * 32);
        f16_t* dst = Rf + r * RP16 + half * 32;
#pragma unroll
        for (int b = 0; b < 4; ++b) {
            float4 f0 = p4[2 * b], f1 = p4[2 * b + 1];
            f16x8 h;
            h[0] = (f16_t)f0.x; h[1] = (f16_t)f0.y; h[2] = (f16_t)f0.z; h[3] = (f16_t)f0.w;
            h[4] = (f16_t)f1.x; h[5] = (f16_t)f1.y; h[6] = (f16_t)f1.z; h[7] = (f16_t)f1.w;
            *(f16x8*)(dst + 8 * b) = h;
        }
    }
    // ---- q' -> Qs (wave-private cols) ----
    if (lane < 32) {
        const float* qp = q_in + (t0 + RB + lane) * 7;
#pragma unroll
        for (int p = 0; p < 7; ++p) Qs[p][RB + lane] = qp[p];
        Qs[7][RB + lane] = 1.0f;
    }

    f32x4 kbv, vbv;
#pragma unroll
    for (int c = 0; c < 4; ++c) { kbv[c] = keyB[16 * c + l15]; vbv[c] = valB[16 * c + l15]; }
    const float sc = scale_p[0];

    // ---- A-fragments (named) ----
    f16x8 ah00 = *(const f16x8*)(Rf + l15 * RP16 + quad * 8);
    f16x8 ah01 = *(const f16x8*)(Rf + l15 * RP16 + 32 + quad * 8);
    f16x8 ah10 = *(const f16x8*)(Rf + (16 + l15) * RP16 + quad * 8);
    f16x8 ah11 = *(const f16x8*)(Rf + (16 + l15) * RP16 + 32 + quad * 8);

    // ---- T stage: q = sum_p q'_p * (KV @ T_p^T), named accumulators ----
    f32x4 q00 = {}, q01 = {}, q02 = {}, q03 = {};
    f32x4 q10 = {}, q11 = {}, q12 = {}, q13 = {};
#pragma unroll 1
    for (int p = 0; p < 8; ++p) {
        const f16_t* bt = wsf + OFF_T + p * 4096;
        f32x4 t00 = {}, t01 = {}, t02 = {}, t03 = {};
        f32x4 t10 = {}, t11 = {}, t12 = {}, t13 = {};
        GEMMC(bt, 0, ah00, ah01, ah10, ah11, t00, t10);
        GEMMC(bt, 1, ah00, ah01, ah10, ah11, t01, t11);
        GEMMC(bt, 2, ah00, ah01, ah10, ah11, t02, t12);
        GEMMC(bt, 3, ah00, ah01, ah10, ah11, t03, t13);
        f32x4 qp0 = *(const f32x4*)&Qs[p][RB + quad * 4];
        f32x4 qp1 = *(const f32x4*)&Qs[p][RB + 16 + quad * 4];
        q00 += qp0 * t00; q01 += qp0 * t01; q02 += qp0 * t02; q03 += qp0 * t03;
        q10 += qp1 * t10; q11 += qp1 * t11; q12 += qp1 * t12; q13 += qp1 * t13;
    }

    // ---- per row-tile front (k|v + elementwise + relay) ----
    front_rt(Rf, wsf, l15, quad, 0,  ah00, ah01, q00, q01, q02, q03, kbv, vbv, sc);
    front_rt(Rf, wsf, l15, quad, 16, ah10, ah11, q10, q11, q12, q13, kbv, vbv, sc);

    // ---- d1: h1 = relu(x @ d1 + b1) ----
    f16x8 xh00 = *(const f16x8*)(Rf + l15 * RP16 + quad * 8);
    f16x8 xh01 = *(const f16x8*)(Rf + l15 * RP16 + 32 + quad * 8);
    f16x8 xh10 = *(const f16x8*)(Rf + (16 + l15) * RP16 + quad * 8);
    f16x8 xh11 = *(const f16x8*)(Rf + (16 + l15) * RP16 + 32 + quad * 8);
    {
        const f16_t* wd1 = wsf + OFF_D1;
        f32x4 h00 = {}, h01 = {}, h02 = {}, h03 = {};
        f32x4 h10 = {}, h11 = {}, h12 = {}, h13 = {};
        GEMMC(wd1, 0, xh00, xh01, xh10, xh11, h00, h10);
        GEMMC(wd1, 1, xh00, xh01, xh10, xh11, h01, h11);
        GEMMC(wd1, 2, xh00, xh01, xh10, xh11, h02, h12);
        GEMMC(wd1, 3, xh00, xh01, xh10, xh11, h03, h13);
        f32x4 b1v;
#pragma unroll
        for (int c = 0; c < 4; ++c) b1v[c] = d1B[16 * c + l15];
#pragma unroll
        for (int e = 0; e < 4; ++e) {
            f16_t* r0 = Rf + (quad * 4 + e) * RP16 + l15;
            r0[0]  = (f16_t)fmaxf(h00[e] + b1v[0], 0.f);
            r0[16] = (f16_t)fmaxf(h01[e] + b1v[1], 0.f);
            r0[32] = (f16_t)fmaxf(h02[e] + b1v[2], 0.f);
            r0[48] = (f16_t)fmaxf(h03[e] + b1v[3], 0.f);
            f16_t* r1 = Rf + (16 + quad * 4 + e) * RP16 + l15;
            r1[0]  = (f16_t)fmaxf(h10[e] + b1v[0], 0.f);
            r1[16] = (f16_t)fmaxf(h11[e] + b1v[1], 0.f);
            r1[32] = (f16_t)fmaxf(h12[e] + b1v[2], 0.f);
            r1[48] = (f16_t)fmaxf(h13[e] + b1v[3], 0.f);
        }
    }

    // ---- d2: h2 = relu(h1 @ d2 + b2), 32 cols ----
    xh00 = *(const f16x8*)(Rf + l15 * RP16 + quad * 8);
    xh01 = *(const f16x8*)(Rf + l15 * RP16 + 32 + quad * 8);
    xh10 = *(const f16x8*)(Rf + (16 + l15) * RP16 + quad * 8);
    xh11 = *(const f16x8*)(Rf + (16 + l15) * RP16 + 32 + quad * 8);
    {
        const f16_t* wd2 = wsf + OFF_D2;
        f32x4 g00 = {}, g01 = {}, g10 = {}, g11 = {};
        GEMMC(wd2, 0, xh00, xh01, xh10, xh11, g00, g10);
        GEMMC(wd2, 1, xh00, xh01, xh10, xh11, g01, g11);
        float b20 = d2B[l15], b21 = d2B[16 + l15];
#pragma unroll
        for (int e = 0; e < 4; ++e) {
            f16_t* r0 = Rf + (quad * 4 + e) * RP16 + l15;
            r0[0]  = (f16_t)fmaxf(g00[e] + b20, 0.f);
            r0[16] = (f16_t)fmaxf(g01[e] + b21, 0.f);
            f16_t* r1 = Rf + (16 + quad * 4 + e) * RP16 + l15;
            r1[0]  = (f16_t)fmaxf(g10[e] + b20, 0.f);
            r1[16] = (f16_t)fmaxf(g11[e] + b21, 0.f);
        }
    }

    // ---- d3: out = h2 @ d3 + b3 (K=32) -> two 16-row halves via slab ----
    f16x8 a30 = *(const f16x8*)(Rf + l15 * RP16 + quad * 8);
    f16x8 a31 = *(const f16x8*)(Rf + (16 + l15) * RP16 + quad * 8);
    f32x4 b3v;
#pragma unroll
    for (int c = 0; c < 4; ++c) b3v[c] = d3B[16 * c + l15];
    float* __restrict__ obase = out + (t0 + RB) * 64;

#pragma unroll
    for (int h = 0; h < 2; ++h) {
        const f16x8 a3 = h ? a31 : a30;
#pragma unroll
        for (int c = 0; c < 4; ++c) {
            f16x8 bw = *(const f16x8*)(wsf + OFF_D3 + (16 * c + l15) * 32 + quad * 8);
            f32x4 z = {};
            f32x4 o = mfma1(a3, bw, z);
#pragma unroll
            for (int e = 0; e < 4; ++e)
                Of[(quad * 4 + e) * OP32 + 16 * c + l15] = o[e] + b3v[c];
        }
        // 16-row half: 4 x 1KB contiguous wave-stores (wave-private, no barrier)
#pragma unroll
        for (int i = 0; i < 4; ++i) {
            const int r4 = i * 4 + quad;
            f32x4 v = *(const f32x4*)(Of + r4 * OP32 + l15 * 4);
            *(f32x4*)(obase + h * 1024 + i * 256 + lane * 4) = v;
        }
    }
}

extern "C" void kernel_launch(void* const* d_in, const int* in_sizes, int n_in,
                              void* d_out, int out_size, void* d_ws, size_t ws_size,
                              hipStream_t stream) {
    (void)in_sizes; (void)n_in; (void)out_size; (void)ws_size;
    const float* kv_in = (const float*)d_in[0];
    const float* q_in  = (const float*)d_in[1];
    const float* keyW  = (const float*)d_in[2];
    const float* keyB  = (const float*)d_in[3];
    const float* valW  = (const float*)d_in[4];
    const float* valB  = (const float*)d_in[5];
    const float* TW    = (const float*)d_in[6];
    const float* TB    = (const float*)d_in[7];
    const float* d1W   = (const float*)d_in[8];
    const float* d1B   = (const float*)d_in[9];
    const float* d2W   = (const float*)d_in[10];
    const float* d2B   = (const float*)d_in[11];
    const float* d3W   = (const float*)d_in[12];
    const float* d3B   = (const float*)d_in[13];
    const float* scale = (const float*)d_in[14];
    f16_t* wsf = (f16_t*)d_ws;
    float* outp = (float*)d_out;

    prep_w<<<(WTOT + 255) / 256, 256, 0, stream>>>(keyW, valW, TW, TB, d1W, d2W, d3W, wsf);
    fused_mfma<<<NTOK / MT, TPB, 0, stream>>>(kv_in, q_in, keyB, valB,
                                              d1B, d2B, d3B, scale, wsf, outp);
}

// Round 3
// 135.506 us; speedup vs baseline: 1.2698x; 1.1734x over previous
//
#include <hip/hip_runtime.h>
#include <math.h>

typedef _Float16 f16_t;
typedef __attribute__((ext_vector_type(8))) _Float16 f16x8;
typedef __attribute__((ext_vector_type(4))) float f32x4;

#define NTOK 131072
#define MT   128      // tokens per block
#define TPB  256      // 4 waves; each wave owns 32 tokens
#define RP16 72       // relay pitch (f16)
#define OP32 68       // out-stage pitch (f32)
#define SLABB 4608    // per-wave slab (relay 32*72*2)

// ws layout (f16 elems)
#define OFF_KEY 0
#define OFF_VAL 4096
#define OFF_T   8192
#define OFF_D1  40960
#define OFF_D2  45056
#define OFF_D3  47104
#define WTOT    49152

__device__ __forceinline__ f32x4 mfma1(f16x8 a, f16x8 b, f32x4 c) {
    return __builtin_amdgcn_mfma_f32_16x16x32_f16(a, b, c, 0, 0, 0);
}

struct B2 { f16x8 b0, b1; };

// LDS B-fragment read, XOR-swizzled (128B-row panels). row=16c+l15 -> row&7==l15&7.
// Swizzle XORs byte bits 4-6 with row&7: lanes of a quad spread over 8 16B slots,
// 2 lanes/slot = free 2-way. Without it: 16-way conflict (all rows same bank).
__device__ __forceinline__ B2 loadB_lds(const f16_t* __restrict__ b, int c, int l15, int quad) {
    const char* base = (const char*)b;
    int o0 = (16 * c + l15) * 128 + quad * 16;
    int sw = (l15 & 7) << 4;
    B2 r;
    r.b0 = *(const f16x8*)(base + (o0 ^ sw));
    r.b1 = *(const f16x8*)(base + ((o0 + 64) ^ sw));
    return r;
}

#define GEMML(buf, c, a00, a01, a10, a11, acc0, acc1) do {        \
    B2 Bf = loadB_lds((buf), (c), l15, quad);                      \
    acc0 = mfma1(a01, Bf.b1, mfma1(a00, Bf.b0, acc0));             \
    acc1 = mfma1(a11, Bf.b1, mfma1(a10, Bf.b0, acc1));             \
} while (0)

// async global->LDS DMA, 16B/lane; LDS dest = wave-uniform base + lane*16 (linear)
__device__ __forceinline__ void gl_lds16(const void* g, void* l) {
    __builtin_amdgcn_global_load_lds(
        (const __attribute__((address_space(1))) unsigned int*)g,
        (__attribute__((address_space(3))) unsigned int*)l, 16, 0, 0);
}

// Stage an 8KB 128B-row panel. LDS written LINEARLY; the swizzle is applied as the
// INVERSE permutation on the global source (involution: g = o ^ ((o>>7 & 7)<<4)),
// so LDS[row][col ^ ((row&7)<<4)] = G[row][col]  == what loadB_lds expects.
__device__ __forceinline__ void stage8k(const f16_t* __restrict__ gsrc, f16_t* lbuf, int tid) {
#pragma unroll
    for (int i = 0; i < 2; ++i) {
        int o = (i * 256 + tid) * 16;
        int g = o ^ (((o >> 7) & 7) << 4);
        gl_lds16((const char*)gsrc + g, (char*)lbuf + (o & ~1023));
    }
}
__device__ __forceinline__ void stage4k_r128(const f16_t* __restrict__ gsrc, f16_t* lbuf, int tid) {
    int o = tid * 16;
    int g = o ^ (((o >> 7) & 7) << 4);
    gl_lds16((const char*)gsrc + g, (char*)lbuf + (o & ~1023));
}
// 64B-row panel (d3): swizzle XORs bits 4-5 with row>>1 (= (o>>7)&3)
__device__ __forceinline__ void stage4k_r64(const f16_t* __restrict__ gsrc, f16_t* lbuf, int tid) {
    int o = tid * 16;
    int g = o ^ (((o >> 7) & 3) << 4);
    gl_lds16((const char*)gsrc + g, (char*)lbuf + (o & ~1023));
}

// counted vmcnt + raw barrier: NEVER __syncthreads() (it drains vmcnt(0) and
// kills the cross-barrier prefetch). "memory" clobber pins load motion.
#define VMW2() asm volatile("s_waitcnt vmcnt(2)" ::: "memory")
#define VMW0() asm volatile("s_waitcnt vmcnt(0)" ::: "memory")
#define BAR()  do { __builtin_amdgcn_s_barrier(); asm volatile("" ::: "memory"); } while (0)

// ---------------- prep: transpose all weights into ws as fp16 --------------
__global__ __launch_bounds__(256)
void prep_w(const float* __restrict__ keyW, const float* __restrict__ valW,
            const float* __restrict__ TW,   const float* __restrict__ TB,
            const float* __restrict__ d1W,  const float* __restrict__ d2W,
            const float* __restrict__ d3W,  f16_t* __restrict__ wsf)
{
    int idx = blockIdx.x * 256 + threadIdx.x;
    if (idx >= WTOT) return;
    float src;
    if (idx < OFF_VAL) {
        int r = idx - OFF_KEY, n = r >> 6, j = r & 63;
        src = keyW[j * 64 + n];
    } else if (idx < OFF_T) {
        int r = idx - OFF_VAL, n = r >> 6, j = r & 63;
        src = valW[j * 64 + n];
    } else if (idx < OFF_D1) {
        int r = idx - OFF_T, p = r >> 12, q = r & 4095;
        src = (p < 7) ? TW[p * 4096 + q] : TB[q];
    } else if (idx < OFF_D2) {
        int r = idx - OFF_D1, n = r >> 6, j = r & 63;
        src = d1W[j * 64 + n];
    } else if (idx < OFF_D3) {
        int r = idx - OFF_D2, n = r >> 6, j = r & 63;
        src = d2W[j * 32 + n];
    } else {
        int r = idx - OFF_D3, n = r >> 5, j = r & 31;
        src = d3W[j * 64 + n];
    }
    wsf[idx] = (f16_t)src;
}

// per-row-tile front: k|v GEMM (from LDS-staged key/val) + softmax + att +
// normalize + relay. All value params, all named locals.
__device__ __forceinline__ void front_rt(
    f16_t* __restrict__ Rf,
    const f16_t* __restrict__ keyb, const f16_t* __restrict__ valb,
    int l15, int quad, int rtb,
    f16x8 a0, f16x8 a1,
    f32x4 q0, f32x4 q1, f32x4 q2, f32x4 q3,
    f32x4 kbv, f32x4 vbv, float sc)
{
    f32x4 k0 = {}, k1 = {}, k2 = {}, k3 = {}, v0 = {}, v1 = {}, v2 = {}, v3 = {};
    { B2 B = loadB_lds(keyb, 0, l15, quad); k0 = mfma1(a1, B.b1, mfma1(a0, B.b0, k0)); }
    { B2 B = loadB_lds(keyb, 1, l15, quad); k1 = mfma1(a1, B.b1, mfma1(a0, B.b0, k1)); }
    { B2 B = loadB_lds(keyb, 2, l15, quad); k2 = mfma1(a1, B.b1, mfma1(a0, B.b0, k2)); }
    { B2 B = loadB_lds(keyb, 3, l15, quad); k3 = mfma1(a1, B.b1, mfma1(a0, B.b0, k3)); }
    { B2 B = loadB_lds(valb, 0, l15, quad); v0 = mfma1(a1, B.b1, mfma1(a0, B.b0, v0)); }
    { B2 B = loadB_lds(valb, 1, l15, quad); v1 = mfma1(a1, B.b1, mfma1(a0, B.b0, v1)); }
    { B2 B = loadB_lds(valb, 2, l15, quad); v2 = mfma1(a1, B.b1, mfma1(a0, B.b0, v2)); }
    { B2 B = loadB_lds(valb, 3, l15, quad); v3 = mfma1(a1, B.b1, mfma1(a0, B.b0, v3)); }

    f32x4 sv0 = (v0 + vbv[0]) * sc;
    f32x4 sv1 = (v1 + vbv[1]) * sc;
    f32x4 sv2 = (v2 + vbv[2]) * sc;
    f32x4 sv3 = (v3 + vbv[3]) * sc;

    f32x4 mx;
#pragma unroll
    for (int e = 0; e < 4; ++e)
        mx[e] = fmaxf(fmaxf(sv0[e], sv1[e]), fmaxf(sv2[e], sv3[e]));
#pragma unroll
    for (int m = 1; m < 16; m <<= 1)
#pragma unroll
        for (int e = 0; e < 4; ++e) mx[e] = fmaxf(mx[e], __shfl_xor(mx[e], m, 64));
#pragma unroll
    for (int e = 0; e < 4; ++e) {
        sv0[e] = __expf(sv0[e] - mx[e]);
        sv1[e] = __expf(sv1[e] - mx[e]);
        sv2[e] = __expf(sv2[e] - mx[e]);
        sv3[e] = __expf(sv3[e] - mx[e]);
    }
    f32x4 se = sv0 + sv1 + sv2 + sv3;
#pragma unroll
    for (int m = 1; m < 16; m <<= 1)
#pragma unroll
        for (int e = 0; e < 4; ++e) se[e] += __shfl_xor(se[e], m, 64);

    f32x4 at0 = q0 * (k0 + kbv[0]);
    f32x4 at1 = q1 * (k1 + kbv[1]);
    f32x4 at2 = q2 * (k2 + kbv[2]);
    f32x4 at3 = q3 * (k3 + kbv[3]);
    f32x4 nr = at0 * at0 + at1 * at1 + at2 * at2 + at3 * at3;
#pragma unroll
    for (int m = 1; m < 16; m <<= 1)
#pragma unroll
        for (int e = 0; e < 4; ++e) nr[e] += __shfl_xor(nr[e], m, 64);

    f32x4 fac;
#pragma unroll
    for (int e = 0; e < 4; ++e)
        fac[e] = 1.0f / (fmaxf(sqrtf(nr[e]), 1e-8f) * se[e]);

#pragma unroll
    for (int e = 0; e < 4; ++e) {
        f16_t* rr = Rf + (rtb + quad * 4 + e) * RP16 + l15;
        rr[0]  = (f16_t)(at0[e] * sv0[e] * fac[e]);
        rr[16] = (f16_t)(at1[e] * sv1[e] * fac[e]);
        rr[32] = (f16_t)(at2[e] * sv2[e] * fac[e]);
        rr[48] = (f16_t)(at3[e] * sv3[e] * fac[e]);
    }
}

// ------- main: block-shared LDS weight staging (double-buffered DMA) -------
// All 4 waves share one staged copy of every weight panel: per-CU weight
// traffic drops 4x and the T-loop reads LDS instead of latency-exposed L2.
__global__ __launch_bounds__(TPB, 2)   // (256,2): natural regalloc, zero spill (R1 lesson)
void fused_mfma(const float* __restrict__ kv_in, const float* __restrict__ q_in,
                const float* __restrict__ keyB,  const float* __restrict__ valB,
                const float* __restrict__ d1B,   const float* __restrict__ d2B,
                const float* __restrict__ d3B,   const float* __restrict__ scale_p,
                const f16_t* __restrict__ wsf,   float* __restrict__ out)
{
    __shared__ __align__(16) unsigned char Slab[4][SLABB];   // 18432 B (wave-private)
    __shared__ __align__(16) float Qs[8][MT];                // 4096 B
    __shared__ __align__(16) f16_t WB[2][4096];              // 16384 B -> 38912 total (4 blk/CU)

    const int tid  = threadIdx.x;
    const int wv   = tid >> 6, lane = tid & 63;
    const int quad = lane >> 4, l15 = lane & 15;
    const int RB   = wv * 32;
    const long t0  = (long)blockIdx.x * MT;

    f16_t* __restrict__ Rf = (f16_t*)Slab[wv];
    float* __restrict__ Of = (float*)Slab[wv];

    // ---- kick off async DMA of T planes 0,1 FIRST (overlaps kv relay) ----
    stage8k(wsf + OFF_T + 0 * 4096, WB[0], tid);
    stage8k(wsf + OFF_T + 1 * 4096, WB[1], tid);

    // ---- coalesced kv staging -> fp16 relay (wave-private) ----
    {
        const int r = lane >> 1, half = lane & 1;
        const float4* p4 = (const float4*)(kv_in + (t0 + RB + r) * 64 + half * 32);
        f16_t* dst = Rf + r * RP16 + half * 32;
#pragma unroll
        for (int b = 0; b < 4; ++b) {
            float4 f0 = p4[2 * b], f1 = p4[2 * b + 1];
            f16x8 h;
            h[0] = (f16_t)f0.x; h[1] = (f16_t)f0.y; h[2] = (f16_t)f0.z; h[3] = (f16_t)f0.w;
            h[4] = (f16_t)f1.x; h[5] = (f16_t)f1.y; h[6] = (f16_t)f1.z; h[7] = (f16_t)f1.w;
            *(f16x8*)(dst + 8 * b) = h;
        }
    }
    // ---- q' -> Qs (wave-private cols) ----
    if (lane < 32) {
        const float* qp = q_in + (t0 + RB + lane) * 7;
#pragma unroll
        for (int p = 0; p < 7; ++p) Qs[p][RB + lane] = qp[p];
        Qs[7][RB + lane] = 1.0f;
    }

    f32x4 kbv, vbv;
#pragma unroll
    for (int c = 0; c < 4; ++c) { kbv[c] = keyB[16 * c + l15]; vbv[c] = valB[16 * c + l15]; }
    const float sc = scale_p[0];

    // ---- A-fragments (named) ----
    f16x8 ah00 = *(const f16x8*)(Rf + l15 * RP16 + quad * 8);
    f16x8 ah01 = *(const f16x8*)(Rf + l15 * RP16 + 32 + quad * 8);
    f16x8 ah10 = *(const f16x8*)(Rf + (16 + l15) * RP16 + quad * 8);
    f16x8 ah11 = *(const f16x8*)(Rf + (16 + l15) * RP16 + 32 + quad * 8);

    // ---- T stage from LDS, double-buffered; DMA plane p+2 during compute p.
    // steady state: vmcnt(2) leaves exactly the newest stage (2 loads) in flight.
    // p==6 stages KEY->WB0, p==7 stages VAL->WB1 (same 8KB 128B-row shape).
    f32x4 q00 = {}, q01 = {}, q02 = {}, q03 = {};
    f32x4 q10 = {}, q11 = {}, q12 = {}, q13 = {};
#pragma unroll 1
    for (int p = 0; p < 8; ++p) {
        const f16_t* tb = WB[p & 1];
        VMW2(); BAR();
        f32x4 t00 = {}, t01 = {}, t02 = {}, t03 = {};
        f32x4 t10 = {}, t11 = {}, t12 = {}, t13 = {};
        GEMML(tb, 0, ah00, ah01, ah10, ah11, t00, t10);
        GEMML(tb, 1, ah00, ah01, ah10, ah11, t01, t11);
        GEMML(tb, 2, ah00, ah01, ah10, ah11, t02, t12);
        GEMML(tb, 3, ah00, ah01, ah10, ah11, t03, t13);
        f32x4 qp0 = *(const f32x4*)&Qs[p][RB + quad * 4];
        f32x4 qp1 = *(const f32x4*)&Qs[p][RB + 16 + quad * 4];
        q00 += qp0 * t00; q01 += qp0 * t01; q02 += qp0 * t02; q03 += qp0 * t03;
        q10 += qp1 * t10; q11 += qp1 * t11; q12 += qp1 * t12; q13 += qp1 * t13;
        BAR();
        const f16_t* nsrc = (p < 6) ? (wsf + OFF_T + (p + 2) * 4096)
                                    : ((p == 6) ? (wsf + OFF_KEY) : (wsf + OFF_VAL));
        stage8k(nsrc, WB[p & 1], tid);
    }
    VMW0(); BAR();   // KEY in WB0, VAL in WB1 ready

    // ---- per row-tile front (k|v from LDS + elementwise + relay) ----
    front_rt(Rf, WB[0], WB[1], l15, quad, 0,  ah00, ah01, q00, q01, q02, q03, kbv, vbv, sc);
    front_rt(Rf, WB[0], WB[1], l15, quad, 16, ah10, ah11, q10, q11, q12, q13, kbv, vbv, sc);
    BAR();           // all waves done reading key/val panels
    stage8k(wsf + OFF_D1, WB[0], tid);                 // d1 -> WB0 (8KB)
    stage4k_r128(wsf + OFF_D2, WB[1], tid);            // d2 -> WB1[0:2048] (4KB)
    stage4k_r64 (wsf + OFF_D3, WB[1] + 2048, tid);     // d3 -> WB1[2048:] (4KB, 64B rows)
    VMW0(); BAR();

    // ---- d1: h1 = relu(x @ d1 + b1) ----
    f16x8 xh00 = *(const f16x8*)(Rf + l15 * RP16 + quad * 8);
    f16x8 xh01 = *(const f16x8*)(Rf + l15 * RP16 + 32 + quad * 8);
    f16x8 xh10 = *(const f16x8*)(Rf + (16 + l15) * RP16 + quad * 8);
    f16x8 xh11 = *(const f16x8*)(Rf + (16 + l15) * RP16 + 32 + quad * 8);
    {
        f32x4 h00 = {}, h01 = {}, h02 = {}, h03 = {};
        f32x4 h10 = {}, h11 = {}, h12 = {}, h13 = {};
        GEMML(WB[0], 0, xh00, xh01, xh10, xh11, h00, h10);
        GEMML(WB[0], 1, xh00, xh01, xh10, xh11, h01, h11);
        GEMML(WB[0], 2, xh00, xh01, xh10, xh11, h02, h12);
        GEMML(WB[0], 3, xh00, xh01, xh10, xh11, h03, h13);
        f32x4 b1v;
#pragma unroll
        for (int c = 0; c < 4; ++c) b1v[c] = d1B[16 * c + l15];
#pragma unroll
        for (int e = 0; e < 4; ++e) {
            f16_t* r0 = Rf + (quad * 4 + e) * RP16 + l15;
            r0[0]  = (f16_t)fmaxf(h00[e] + b1v[0], 0.f);
            r0[16] = (f16_t)fmaxf(h01[e] + b1v[1], 0.f);
            r0[32] = (f16_t)fmaxf(h02[e] + b1v[2], 0.f);
            r0[48] = (f16_t)fmaxf(h03[e] + b1v[3], 0.f);
            f16_t* r1 = Rf + (16 + quad * 4 + e) * RP16 + l15;
            r1[0]  = (f16_t)fmaxf(h10[e] + b1v[0], 0.f);
            r1[16] = (f16_t)fmaxf(h11[e] + b1v[1], 0.f);
            r1[32] = (f16_t)fmaxf(h12[e] + b1v[2], 0.f);
            r1[48] = (f16_t)fmaxf(h13[e] + b1v[3], 0.f);
        }
    }

    // ---- d2: h2 = relu(h1 @ d2 + b2), 32 cols ----
    xh00 = *(const f16x8*)(Rf + l15 * RP16 + quad * 8);
    xh01 = *(const f16x8*)(Rf + l15 * RP16 + 32 + quad * 8);
    xh10 = *(const f16x8*)(Rf + (16 + l15) * RP16 + quad * 8);
    xh11 = *(const f16x8*)(Rf + (16 + l15) * RP16 + 32 + quad * 8);
    {
        f32x4 g00 = {}, g01 = {}, g10 = {}, g11 = {};
        GEMML(WB[1], 0, xh00, xh01, xh10, xh11, g00, g10);
        GEMML(WB[1], 1, xh00, xh01, xh10, xh11, g01, g11);
        float b20 = d2B[l15], b21 = d2B[16 + l15];
#pragma unroll
        for (int e = 0; e < 4; ++e) {
            f16_t* r0 = Rf + (quad * 4 + e) * RP16 + l15;
            r0[0]  = (f16_t)fmaxf(g00[e] + b20, 0.f);
            r0[16] = (f16_t)fmaxf(g01[e] + b21, 0.f);
            f16_t* r1 = Rf + (16 + quad * 4 + e) * RP16 + l15;
            r1[0]  = (f16_t)fmaxf(g10[e] + b20, 0.f);
            r1[16] = (f16_t)fmaxf(g11[e] + b21, 0.f);
        }
    }

    // ---- d3: out = h2 @ d3 + b3 (K=32), weights from WB1[2048:] (64B rows) ----
    f16x8 a30 = *(const f16x8*)(Rf + l15 * RP16 + quad * 8);
    f16x8 a31 = *(const f16x8*)(Rf + (16 + l15) * RP16 + quad * 8);
    f32x4 b3v;
#pragma unroll
    for (int c = 0; c < 4; ++c) b3v[c] = d3B[16 * c + l15];
    float* __restrict__ obase = out + (t0 + RB) * 64;
    const char* d3b = (const char*)(&WB[1][2048]);
    const int sw3 = ((l15 >> 1) & 3) << 4;

#pragma unroll
    for (int h = 0; h < 2; ++h) {
        const f16x8 a3 = h ? a31 : a30;
#pragma unroll
        for (int c = 0; c < 4; ++c) {
            int o3 = (16 * c + l15) * 64 + quad * 16;
            f16x8 bw = *(const f16x8*)(d3b + (o3 ^ sw3));
            f32x4 z = {};
            f32x4 o = mfma1(a3, bw, z);
#pragma unroll
            for (int e = 0; e < 4; ++e)
                Of[(quad * 4 + e) * OP32 + 16 * c + l15] = o[e] + b3v[c];
        }
        // 16-row half: 4 x 1KB contiguous wave-stores (wave-private slab)
#pragma unroll
        for (int i = 0; i < 4; ++i) {
            const int r4 = i * 4 + quad;
            f32x4 v = *(const f32x4*)(Of + r4 * OP32 + l15 * 4);
            *(f32x4*)(obase + h * 1024 + i * 256 + lane * 4) = v;
        }
    }
}

extern "C" void kernel_launch(void* const* d_in, const int* in_sizes, int n_in,
                              void* d_out, int out_size, void* d_ws, size_t ws_size,
                              hipStream_t stream) {
    (void)in_sizes; (void)n_in; (void)out_size; (void)ws_size;
    const float* kv_in = (const float*)d_in[0];
    const float* q_in  = (const float*)d_in[1];
    const float* keyW  = (const float*)d_in[2];
    const float* keyB  = (const float*)d_in[3];
    const float* valW  = (const float*)d_in[4];
    const float* valB  = (const float*)d_in[5];
    const float* TW    = (const float*)d_in[6];
    const float* TB    = (const float*)d_in[7];
    const float* d1W   = (const float*)d_in[8];
    const float* d1B   = (const float*)d_in[9];
    const float* d2W   = (const float*)d_in[10];
    const float* d2B   = (const float*)d_in[11];
    const float* d3W   = (const float*)d_in[12];
    const float* d3B   = (const float*)d_in[13];
    const float* scale = (const float*)d_in[14];
    f16_t* wsf = (f16_t*)d_ws;
    float* outp = (float*)d_out;

    prep_w<<<(WTOT + 255) / 256, 256, 0, stream>>>(keyW, valW, TW, TB, d1W, d2W, d3W, wsf);
    fused_mfma<<<NTOK / MT, TPB, 0, stream>>>(kv_in, q_in, keyB, valB,
                                              d1B, d2B, d3B, scale, wsf, outp);
}

// Round 4
// 129.971 us; speedup vs baseline: 1.3238x; 1.0426x over previous
//
#include <hip/hip_runtime.h>
#include <math.h>

typedef _Float16 f16_t;
typedef __attribute__((ext_vector_type(8))) _Float16 f16x8;
typedef __attribute__((ext_vector_type(4))) float f32x4;

#define NTOK 131072
#define MT   256      // tokens per block
#define TPB  256      // 4 waves; each wave owns 64 tokens (M=64 tile)
#define RP16 72       // relay pitch (f16)
#define OP32 68       // out-stage pitch (f32)
#define SLABB 9216    // per-wave slab: relay 64*72*2

// ws layout (f16 elems)
#define OFF_KEY 0
#define OFF_VAL 4096
#define OFF_T   8192
#define OFF_D1  40960
#define OFF_D2  45056
#define OFF_D3  47104
#define WTOT    49152

__device__ __forceinline__ f32x4 mfma1(f16x8 a, f16x8 b, f32x4 c) {
    return __builtin_amdgcn_mfma_f32_16x16x32_f16(a, b, c, 0, 0, 0);
}

struct B2 { f16x8 b0, b1; };

// LDS B-fragment read, XOR-swizzled (128B-row panels). Proven conflict-clean in R3.
__device__ __forceinline__ B2 loadB_lds(const f16_t* __restrict__ b, int c, int l15, int quad) {
    const char* base = (const char*)b;
    int o0 = (16 * c + l15) * 128 + quad * 16;
    int sw = (l15 & 7) << 4;
    B2 r;
    r.b0 = *(const f16x8*)(base + (o0 ^ sw));
    r.b1 = *(const f16x8*)(base + ((o0 + 64) ^ sw));
    return r;
}

#define GEMML(buf, c, a00, a01, a10, a11, acc0, acc1) do {        \
    B2 Bf = loadB_lds((buf), (c), l15, quad);                      \
    acc0 = mfma1(a01, Bf.b1, mfma1(a00, Bf.b0, acc0));             \
    acc1 = mfma1(a11, Bf.b1, mfma1(a10, Bf.b0, acc1));             \
} while (0)

// T-stage column step: ONE B-fragment pair feeds FOUR row-tiles (B-reuse=4),
// and each t is consumed immediately into its q accumulator (t dies at once).
#define TCOL(tb, c, QA0, QA1, QA2, QA3, Q0, Q1, Q2, Q3) do {       \
    B2 Bf = loadB_lds((tb), (c), l15, quad);                        \
    f32x4 z = {};                                                   \
    f32x4 tt0 = mfma1(ah01, Bf.b1, mfma1(ah00, Bf.b0, z));          \
    Q0 += QA0 * tt0;                                                \
    f32x4 tt1 = mfma1(ah11, Bf.b1, mfma1(ah10, Bf.b0, z));          \
    Q1 += QA1 * tt1;                                                \
    f32x4 tt2 = mfma1(ah21, Bf.b1, mfma1(ah20, Bf.b0, z));          \
    Q2 += QA2 * tt2;                                                \
    f32x4 tt3 = mfma1(ah31, Bf.b1, mfma1(ah30, Bf.b0, z));          \
    Q3 += QA3 * tt3;                                                \
} while (0)

// async global->LDS DMA, 16B/lane; LDS dest linear (base + lane*16)
__device__ __forceinline__ void gl_lds16(const void* g, void* l) {
    __builtin_amdgcn_global_load_lds(
        (const __attribute__((address_space(1))) unsigned int*)g,
        (__attribute__((address_space(3))) unsigned int*)l, 16, 0, 0);
}

// Stage an 8KB 128B-row panel; swizzle applied as inverse perm on the GLOBAL src
// (both-sides-or-neither rule): LDS[row][col ^ ((row&7)<<4)] = G[row][col].
__device__ __forceinline__ void stage8k(const f16_t* __restrict__ gsrc, f16_t* lbuf, int tid) {
#pragma unroll
    for (int i = 0; i < 2; ++i) {
        int o = (i * 256 + tid) * 16;
        int g = o ^ (((o >> 7) & 7) << 4);
        gl_lds16((const char*)gsrc + g, (char*)lbuf + (o & ~1023));
    }
}
__device__ __forceinline__ void stage4k_r128(const f16_t* __restrict__ gsrc, f16_t* lbuf, int tid) {
    int o = tid * 16;
    int g = o ^ (((o >> 7) & 7) << 4);
    gl_lds16((const char*)gsrc + g, (char*)lbuf + (o & ~1023));
}
// 64B-row panel (d3): swizzle XORs bits 4-5 with row>>1
__device__ __forceinline__ void stage4k_r64(const f16_t* __restrict__ gsrc, f16_t* lbuf, int tid) {
    int o = tid * 16;
    int g = o ^ (((o >> 7) & 3) << 4);
    gl_lds16((const char*)gsrc + g, (char*)lbuf + (o & ~1023));
}

// counted vmcnt + raw barrier (NEVER __syncthreads: it drains vmcnt(0))
#define VMW2() asm volatile("s_waitcnt vmcnt(2)" ::: "memory")
#define VMW0() asm volatile("s_waitcnt vmcnt(0)" ::: "memory")
#define BAR()  do { __builtin_amdgcn_s_barrier(); asm volatile("" ::: "memory"); } while (0)

// ---------------- prep: transpose all weights into ws as fp16 --------------
__global__ __launch_bounds__(256)
void prep_w(const float* __restrict__ keyW, const float* __restrict__ valW,
            const float* __restrict__ TW,   const float* __restrict__ TB,
            const float* __restrict__ d1W,  const float* __restrict__ d2W,
            const float* __restrict__ d3W,  f16_t* __restrict__ wsf)
{
    int idx = blockIdx.x * 256 + threadIdx.x;
    if (idx >= WTOT) return;
    float src;
    if (idx < OFF_VAL) {
        int r = idx - OFF_KEY, n = r >> 6, j = r & 63;
        src = keyW[j * 64 + n];
    } else if (idx < OFF_T) {
        int r = idx - OFF_VAL, n = r >> 6, j = r & 63;
        src = valW[j * 64 + n];
    } else if (idx < OFF_D1) {
        int r = idx - OFF_T, p = r >> 12, q = r & 4095;
        src = (p < 7) ? TW[p * 4096 + q] : TB[q];
    } else if (idx < OFF_D2) {
        int r = idx - OFF_D1, n = r >> 6, j = r & 63;
        src = d1W[j * 64 + n];
    } else if (idx < OFF_D3) {
        int r = idx - OFF_D2, n = r >> 6, j = r & 63;
        src = d2W[j * 32 + n];
    } else {
        int r = idx - OFF_D3, n = r >> 5, j = r & 31;
        src = d3W[j * 64 + n];
    }
    wsf[idx] = (f16_t)src;
}

// per-row-tile front: k|v GEMM (LDS-staged) + softmax + att + normalize + relay.
__device__ __forceinline__ void front_rt(
    f16_t* __restrict__ Rf,
    const f16_t* __restrict__ keyb, const f16_t* __restrict__ valb,
    int l15, int quad, int rtb,
    f16x8 a0, f16x8 a1,
    f32x4 q0, f32x4 q1, f32x4 q2, f32x4 q3,
    f32x4 kbv, f32x4 vbv, float sc)
{
    f32x4 k0 = {}, k1 = {}, k2 = {}, k3 = {}, v0 = {}, v1 = {}, v2 = {}, v3 = {};
    { B2 B = loadB_lds(keyb, 0, l15, quad); k0 = mfma1(a1, B.b1, mfma1(a0, B.b0, k0)); }
    { B2 B = loadB_lds(keyb, 1, l15, quad); k1 = mfma1(a1, B.b1, mfma1(a0, B.b0, k1)); }
    { B2 B = loadB_lds(keyb, 2, l15, quad); k2 = mfma1(a1, B.b1, mfma1(a0, B.b0, k2)); }
    { B2 B = loadB_lds(keyb, 3, l15, quad); k3 = mfma1(a1, B.b1, mfma1(a0, B.b0, k3)); }
    { B2 B = loadB_lds(valb, 0, l15, quad); v0 = mfma1(a1, B.b1, mfma1(a0, B.b0, v0)); }
    { B2 B = loadB_lds(valb, 1, l15, quad); v1 = mfma1(a1, B.b1, mfma1(a0, B.b0, v1)); }
    { B2 B = loadB_lds(valb, 2, l15, quad); v2 = mfma1(a1, B.b1, mfma1(a0, B.b0, v2)); }
    { B2 B = loadB_lds(valb, 3, l15, quad); v3 = mfma1(a1, B.b1, mfma1(a0, B.b0, v3)); }

    f32x4 sv0 = (v0 + vbv[0]) * sc;
    f32x4 sv1 = (v1 + vbv[1]) * sc;
    f32x4 sv2 = (v2 + vbv[2]) * sc;
    f32x4 sv3 = (v3 + vbv[3]) * sc;

    f32x4 mx;
#pragma unroll
    for (int e = 0; e < 4; ++e)
        mx[e] = fmaxf(fmaxf(sv0[e], sv1[e]), fmaxf(sv2[e], sv3[e]));
#pragma unroll
    for (int m = 1; m < 16; m <<= 1)
#pragma unroll
        for (int e = 0; e < 4; ++e) mx[e] = fmaxf(mx[e], __shfl_xor(mx[e], m, 64));
#pragma unroll
    for (int e = 0; e < 4; ++e) {
        sv0[e] = __expf(sv0[e] - mx[e]);
        sv1[e] = __expf(sv1[e] - mx[e]);
        sv2[e] = __expf(sv2[e] - mx[e]);
        sv3[e] = __expf(sv3[e] - mx[e]);
    }
    f32x4 se = sv0 + sv1 + sv2 + sv3;
#pragma unroll
    for (int m = 1; m < 16; m <<= 1)
#pragma unroll
        for (int e = 0; e < 4; ++e) se[e] += __shfl_xor(se[e], m, 64);

    f32x4 at0 = q0 * (k0 + kbv[0]);
    f32x4 at1 = q1 * (k1 + kbv[1]);
    f32x4 at2 = q2 * (k2 + kbv[2]);
    f32x4 at3 = q3 * (k3 + kbv[3]);
    f32x4 nr = at0 * at0 + at1 * at1 + at2 * at2 + at3 * at3;
#pragma unroll
    for (int m = 1; m < 16; m <<= 1)
#pragma unroll
        for (int e = 0; e < 4; ++e) nr[e] += __shfl_xor(nr[e], m, 64);

    f32x4 fac;
#pragma unroll
    for (int e = 0; e < 4; ++e)
        fac[e] = 1.0f / (fmaxf(sqrtf(nr[e]), 1e-8f) * se[e]);

#pragma unroll
    for (int e = 0; e < 4; ++e) {
        f16_t* rr = Rf + (rtb + quad * 4 + e) * RP16 + l15;
        rr[0]  = (f16_t)(at0[e] * sv0[e] * fac[e]);
        rr[16] = (f16_t)(at1[e] * sv1[e] * fac[e]);
        rr[32] = (f16_t)(at2[e] * sv2[e] * fac[e]);
        rr[48] = (f16_t)(at3[e] * sv3[e] * fac[e]);
    }
}

// 32-row d1 pass: h1 = relu(x @ d1 + b1), relay in-place
__device__ __forceinline__ void d1_rt(f16_t* __restrict__ Rf, const f16_t* __restrict__ wb,
                                      int l15, int quad, int rtb, f32x4 b1v)
{
    f16x8 x00 = *(const f16x8*)(Rf + (rtb + l15) * RP16 + quad * 8);
    f16x8 x01 = *(const f16x8*)(Rf + (rtb + l15) * RP16 + 32 + quad * 8);
    f16x8 x10 = *(const f16x8*)(Rf + (rtb + 16 + l15) * RP16 + quad * 8);
    f16x8 x11 = *(const f16x8*)(Rf + (rtb + 16 + l15) * RP16 + 32 + quad * 8);
    f32x4 h00 = {}, h01 = {}, h02 = {}, h03 = {};
    f32x4 h10 = {}, h11 = {}, h12 = {}, h13 = {};
    GEMML(wb, 0, x00, x01, x10, x11, h00, h10);
    GEMML(wb, 1, x00, x01, x10, x11, h01, h11);
    GEMML(wb, 2, x00, x01, x10, x11, h02, h12);
    GEMML(wb, 3, x00, x01, x10, x11, h03, h13);
#pragma unroll
    for (int e = 0; e < 4; ++e) {
        f16_t* r0 = Rf + (rtb + quad * 4 + e) * RP16 + l15;
        r0[0]  = (f16_t)fmaxf(h00[e] + b1v[0], 0.f);
        r0[16] = (f16_t)fmaxf(h01[e] + b1v[1], 0.f);
        r0[32] = (f16_t)fmaxf(h02[e] + b1v[2], 0.f);
        r0[48] = (f16_t)fmaxf(h03[e] + b1v[3], 0.f);
        f16_t* r1 = Rf + (rtb + 16 + quad * 4 + e) * RP16 + l15;
        r1[0]  = (f16_t)fmaxf(h10[e] + b1v[0], 0.f);
        r1[16] = (f16_t)fmaxf(h11[e] + b1v[1], 0.f);
        r1[32] = (f16_t)fmaxf(h12[e] + b1v[2], 0.f);
        r1[48] = (f16_t)fmaxf(h13[e] + b1v[3], 0.f);
    }
}

// 32-row d2 pass: h2 = relu(h1 @ d2 + b2), 32 cols
__device__ __forceinline__ void d2_rt(f16_t* __restrict__ Rf, const f16_t* __restrict__ wb,
                                      int l15, int quad, int rtb, float b20, float b21)
{
    f16x8 x00 = *(const f16x8*)(Rf + (rtb + l15) * RP16 + quad * 8);
    f16x8 x01 = *(const f16x8*)(Rf + (rtb + l15) * RP16 + 32 + quad * 8);
    f16x8 x10 = *(const f16x8*)(Rf + (rtb + 16 + l15) * RP16 + quad * 8);
    f16x8 x11 = *(const f16x8*)(Rf + (rtb + 16 + l15) * RP16 + 32 + quad * 8);
    f32x4 g00 = {}, g01 = {}, g10 = {}, g11 = {};
    GEMML(wb, 0, x00, x01, x10, x11, g00, g10);
    GEMML(wb, 1, x00, x01, x10, x11, g01, g11);
#pragma unroll
    for (int e = 0; e < 4; ++e) {
        f16_t* r0 = Rf + (rtb + quad * 4 + e) * RP16 + l15;
        r0[0]  = (f16_t)fmaxf(g00[e] + b20, 0.f);
        r0[16] = (f16_t)fmaxf(g01[e] + b21, 0.f);
        f16_t* r1 = Rf + (rtb + 16 + quad * 4 + e) * RP16 + l15;
        r1[0]  = (f16_t)fmaxf(g10[e] + b20, 0.f);
        r1[16] = (f16_t)fmaxf(g11[e] + b21, 0.f);
    }
}

// 32-row d3 pass: out = h2 @ d3 + b3 (K=32) -> two 16-row staged stores.
// Of occupies slab bytes [0,4352) = relay rows 0..30: safe because this pass's
// A-frags are already in regs, and the rtb=32 pass reads rows 32+ (bytes 4608+).
__device__ __forceinline__ void d3_rt(f16_t* __restrict__ Rf, float* __restrict__ Of,
                                      const char* __restrict__ d3b,
                                      int l15, int quad, int lane, int rtb,
                                      f32x4 b3v, float* __restrict__ obase)
{
    f16x8 a30 = *(const f16x8*)(Rf + (rtb + l15) * RP16 + quad * 8);
    f16x8 a31 = *(const f16x8*)(Rf + (rtb + 16 + l15) * RP16 + quad * 8);
    const int sw3 = ((l15 >> 1) & 3) << 4;
#pragma unroll
    for (int h = 0; h < 2; ++h) {
        const f16x8 a3 = h ? a31 : a30;
#pragma unroll
        for (int c = 0; c < 4; ++c) {
            int o3 = (16 * c + l15) * 64 + quad * 16;
            f16x8 bw = *(const f16x8*)(d3b + (o3 ^ sw3));
            f32x4 z = {};
            f32x4 o = mfma1(a3, bw, z);
#pragma unroll
            for (int e = 0; e < 4; ++e)
                Of[(quad * 4 + e) * OP32 + 16 * c + l15] = o[e] + b3v[c];
        }
#pragma unroll
        for (int i = 0; i < 4; ++i) {
            const int r4 = i * 4 + quad;
            f32x4 v = *(const f32x4*)(Of + r4 * OP32 + l15 * 4);
            *(f32x4*)(obase + rtb * 64 + h * 1024 + i * 256 + lane * 4) = v;
        }
    }
}

// ------- main: M=64/wave tile (B-reuse 4), block-shared LDS weight DMA -----
__global__ __launch_bounds__(TPB, 2)   // natural regalloc; spill tripwire = WRITE_SIZE
void fused_mfma(const float* __restrict__ kv_in, const float* __restrict__ q_in,
                const float* __restrict__ keyB,  const float* __restrict__ valB,
                const float* __restrict__ d1B,   const float* __restrict__ d2B,
                const float* __restrict__ d3B,   const float* __restrict__ scale_p,
                const f16_t* __restrict__ wsf,   float* __restrict__ out)
{
    __shared__ __align__(16) unsigned char Slab[4][SLABB];   // 36864 B (wave-private)
    __shared__ __align__(16) float Qs[8][MT];                // 8192 B
    __shared__ __align__(16) f16_t WB[2][4096];              // 16384 B -> 61440 total (2 blk/CU)

    const int tid  = threadIdx.x;
    const int wv   = tid >> 6, lane = tid & 63;
    const int quad = lane >> 4, l15 = lane & 15;
    const int RB   = wv * 64;
    const long t0  = (long)blockIdx.x * MT;

    f16_t* __restrict__ Rf = (f16_t*)Slab[wv];
    float* __restrict__ Of = (float*)Slab[wv];

    // ---- kick off async DMA of T planes 0,1 FIRST (oldest in vmcnt queue) ----
    stage8k(wsf + OFF_T + 0 * 4096, WB[0], tid);
    stage8k(wsf + OFF_T + 1 * 4096, WB[1], tid);

    // ---- small params early (L2 loads overlap relay) ----
    f32x4 kbv, vbv, b1v, b3v;
#pragma unroll
    for (int c = 0; c < 4; ++c) {
        kbv[c] = keyB[16 * c + l15];  vbv[c] = valB[16 * c + l15];
        b1v[c] = d1B[16 * c + l15];   b3v[c] = d3B[16 * c + l15];
    }
    const float b20 = d2B[l15], b21 = d2B[16 + l15];
    const float sc = scale_p[0];

    // ---- coalesced kv staging -> fp16 relay, 64 rows/wave ----
    {
        const int r = lane >> 1, half = lane & 1;
#pragma unroll
        for (int s = 0; s < 2; ++s) {
            const float4* p4 = (const float4*)(kv_in + (t0 + RB + s * 32 + r) * 64 + half * 32);
            f16_t* dst = Rf + (s * 32 + r) * RP16 + half * 32;
#pragma unroll
            for (int b = 0; b < 4; ++b) {
                float4 f0 = p4[2 * b], f1 = p4[2 * b + 1];
                f16x8 h;
                h[0] = (f16_t)f0.x; h[1] = (f16_t)f0.y; h[2] = (f16_t)f0.z; h[3] = (f16_t)f0.w;
                h[4] = (f16_t)f1.x; h[5] = (f16_t)f1.y; h[6] = (f16_t)f1.z; h[7] = (f16_t)f1.w;
                *(f16x8*)(dst + 8 * b) = h;
            }
        }
    }
    // ---- q' -> Qs (all 64 lanes, 64 tokens/wave) ----
    {
        const float* qp = q_in + (t0 + RB + lane) * 7;
#pragma unroll
        for (int p = 0; p < 7; ++p) Qs[p][RB + lane] = qp[p];
        Qs[7][RB + lane] = 1.0f;
    }

    // ---- A-fragments: 4 row-tiles x 2 halves (named) ----
    f16x8 ah00 = *(const f16x8*)(Rf + l15 * RP16 + quad * 8);
    f16x8 ah01 = *(const f16x8*)(Rf + l15 * RP16 + 32 + quad * 8);
    f16x8 ah10 = *(const f16x8*)(Rf + (16 + l15) * RP16 + quad * 8);
    f16x8 ah11 = *(const f16x8*)(Rf + (16 + l15) * RP16 + 32 + quad * 8);
    f16x8 ah20 = *(const f16x8*)(Rf + (32 + l15) * RP16 + quad * 8);
    f16x8 ah21 = *(const f16x8*)(Rf + (32 + l15) * RP16 + 32 + quad * 8);
    f16x8 ah30 = *(const f16x8*)(Rf + (48 + l15) * RP16 + quad * 8);
    f16x8 ah31 = *(const f16x8*)(Rf + (48 + l15) * RP16 + 32 + quad * 8);

    // ---- T stage, double-buffered DMA; plane p+2 staged during compute p ----
    f32x4 q00 = {}, q01 = {}, q02 = {}, q03 = {};
    f32x4 q10 = {}, q11 = {}, q12 = {}, q13 = {};
    f32x4 q20 = {}, q21 = {}, q22 = {}, q23 = {};
    f32x4 q30 = {}, q31 = {}, q32 = {}, q33 = {};
#pragma unroll 1
    for (int p = 0; p < 8; ++p) {
        const f16_t* tb = WB[p & 1];
        VMW2(); BAR();
        f32x4 qa0 = *(const f32x4*)&Qs[p][RB + quad * 4];
        f32x4 qa1 = *(const f32x4*)&Qs[p][RB + 16 + quad * 4];
        f32x4 qa2 = *(const f32x4*)&Qs[p][RB + 32 + quad * 4];
        f32x4 qa3 = *(const f32x4*)&Qs[p][RB + 48 + quad * 4];
        TCOL(tb, 0, qa0, qa1, qa2, qa3, q00, q10, q20, q30);
        TCOL(tb, 1, qa0, qa1, qa2, qa3, q01, q11, q21, q31);
        TCOL(tb, 2, qa0, qa1, qa2, qa3, q02, q12, q22, q32);
        TCOL(tb, 3, qa0, qa1, qa2, qa3, q03, q13, q23, q33);
        BAR();
        const f16_t* nsrc = (p < 6) ? (wsf + OFF_T + (p + 2) * 4096)
                                    : ((p == 6) ? (wsf + OFF_KEY) : (wsf + OFF_VAL));
        stage8k(nsrc, WB[p & 1], tid);
    }
    VMW0(); BAR();   // KEY in WB0, VAL in WB1 ready

    // ---- fronts: 4 independent row-tiles (k|v + softmax + att + relay) ----
    front_rt(Rf, WB[0], WB[1], l15, quad, 0,  ah00, ah01, q00, q01, q02, q03, kbv, vbv, sc);
    front_rt(Rf, WB[0], WB[1], l15, quad, 16, ah10, ah11, q10, q11, q12, q13, kbv, vbv, sc);
    front_rt(Rf, WB[0], WB[1], l15, quad, 32, ah20, ah21, q20, q21, q22, q23, kbv, vbv, sc);
    front_rt(Rf, WB[0], WB[1], l15, quad, 48, ah30, ah31, q30, q31, q32, q33, kbv, vbv, sc);
    BAR();           // all waves done reading key/val panels
    stage8k(wsf + OFF_D1, WB[0], tid);                 // d1 -> WB0 (8KB)
    stage4k_r128(wsf + OFF_D2, WB[1], tid);            // d2 -> WB1[0:2048] (4KB)
    stage4k_r64 (wsf + OFF_D3, WB[1] + 2048, tid);     // d3 -> WB1[2048:] (4KB, 64B rows)
    VMW0(); BAR();

    // ---- d-chain: two 32-row passes per layer (wave-private, no barriers) ----
    d1_rt(Rf, WB[0], l15, quad, 0,  b1v);
    d1_rt(Rf, WB[0], l15, quad, 32, b1v);
    d2_rt(Rf, WB[1], l15, quad, 0,  b20, b21);
    d2_rt(Rf, WB[1], l15, quad, 32, b20, b21);

    float* __restrict__ obase = out + (t0 + RB) * 64;
    const char* d3b = (const char*)(&WB[1][2048]);
    d3_rt(Rf, Of, d3b, l15, quad, lane, 0,  b3v, obase);
    d3_rt(Rf, Of, d3b, l15, quad, lane, 32, b3v, obase);
}

extern "C" void kernel_launch(void* const* d_in, const int* in_sizes, int n_in,
                              void* d_out, int out_size, void* d_ws, size_t ws_size,
                              hipStream_t stream) {
    (void)in_sizes; (void)n_in; (void)out_size; (void)ws_size;
    const float* kv_in = (const float*)d_in[0];
    const float* q_in  = (const float*)d_in[1];
    const float* keyW  = (const float*)d_in[2];
    const float* keyB  = (const float*)d_in[3];
    const float* valW  = (const float*)d_in[4];
    const float* valB  = (const float*)d_in[5];
    const float* TW    = (const float*)d_in[6];
    const float* TB    = (const float*)d_in[7];
    const float* d1W   = (const float*)d_in[8];
    const float* d1B   = (const float*)d_in[9];
    const float* d2W   = (const float*)d_in[10];
    const float* d2B   = (const float*)d_in[11];
    const float* d3W   = (const float*)d_in[12];
    const float* d3B   = (const float*)d_in[13];
    const float* scale = (const float*)d_in[14];
    f16_t* wsf = (f16_t*)d_ws;
    float* outp = (float*)d_out;

    prep_w<<<(WTOT + 255) / 256, 256, 0, stream>>>(keyW, valW, TW, TB, d1W, d2W, d3W, wsf);
    fused_mfma<<<NTOK / MT, TPB, 0, stream>>>(kv_in, q_in, keyB, valB,
                                              d1B, d2B, d3B, scale, wsf, outp);
}